// Round 5
// baseline (462.493 us; speedup 1.0000x reference)
//
#include <hip/hip_runtime.h>
#include <stdint.h>

typedef unsigned short u16;
typedef unsigned int u32;

constexpr int CB = 2, CT = 2048, CH = 16, CDH = 64, CD = 1024;

typedef __attribute__((ext_vector_type(8))) short bf16x8;
typedef __attribute__((ext_vector_type(4))) float f32x4;
typedef __attribute__((ext_vector_type(16))) float f32x16;

typedef __attribute__((address_space(1))) const u32 as1_cu32;
typedef __attribute__((address_space(3))) u32 as3_u32;

__device__ __forceinline__ void gload_lds16(const void* g, void* l) {
  __builtin_amdgcn_global_load_lds((as1_cu32*)g, (as3_u32*)l, 16, 0, 0);
}

// fp32 -> bf16 round-to-nearest-even (finite inputs only)
__device__ __forceinline__ u16 f2b(float f) {
  u32 x = __float_as_uint(f);
  u32 r = (x + 0x7fffu + ((x >> 16) & 1u)) >> 16;
  return (u16)r;
}

#if __has_builtin(__builtin_amdgcn_cvt_pk_bf16_f32)
typedef __attribute__((ext_vector_type(2))) __bf16 v2bf;
__device__ __forceinline__ u32 pk2(float a, float b) {
  v2bf r = __builtin_amdgcn_cvt_pk_bf16_f32(a, b);
  union { v2bf v; u32 u; } cv; cv.v = r; return cv.u;
}
#else
__device__ __forceinline__ u32 pk2(float a, float b) {
  return (u32)f2b(a) | ((u32)f2b(b) << 16);
}
#endif

__device__ __forceinline__ float b2f(u32 lo16) { return __uint_as_float(lo16 << 16); }

// exp2 (v_exp_f32 is natively base-2)
__device__ __forceinline__ float fexp2(float x) {
#if __has_builtin(__builtin_amdgcn_exp2f)
  return __builtin_amdgcn_exp2f(x);
#else
  return __expf(x * 0.69314718056f);
#endif
}

__device__ __forceinline__ void store_out(u16* p, float v) { *p = f2b(v); }
__device__ __forceinline__ void store_out(float* p, float v) { *p = v; }

// half-swap: a' = {a.lo32lanes, b.lo32lanes}, b' = {a.hi, b.hi}
#if __has_builtin(__builtin_amdgcn_permlane32_swap)
__device__ __forceinline__ void plswap(u32& a, u32& b, int) {
  auto r = __builtin_amdgcn_permlane32_swap(a, b, false, false);
  a = (u32)r[0]; b = (u32)r[1];
}
#else
__device__ __forceinline__ void plswap(u32& a, u32& b, int hf) {
  u32 ta = (u32)__shfl_xor((int)a, 32, 64);
  u32 tb = (u32)__shfl_xor((int)b, 32, 64);
  u32 na = hf ? tb : a;
  u32 nb = hf ? b : ta;
  a = na; b = nb;
}
#endif

// ---------------- fused prep: cast x + transpose/cast 4 weight mats ----------------
__global__ __launch_bounds__(256) void prep_k(const float* __restrict__ x,
                                              const float* __restrict__ Wq,
                                              const float* __restrict__ Wk,
                                              const float* __restrict__ Wv,
                                              const float* __restrict__ Wo,
                                              u16* __restrict__ Xb,
                                              u16* __restrict__ Wt) {
  __shared__ float tile[32][33];
  int bid = blockIdx.x, t = threadIdx.x;
  if (bid < 4096) {
    int i = bid * 256 + t;
    float4 v = ((const float4*)x)[i];
    ushort4 r;
    r.x = f2b(v.x); r.y = f2b(v.y); r.z = f2b(v.z); r.w = f2b(v.w);
    ((ushort4*)Xb)[i] = r;
  } else {
    int tid2 = bid - 4096;
    int mat = tid2 >> 10, b2 = tid2 & 1023;
    const float* W = (mat == 0) ? Wq : (mat == 1) ? Wk : (mat == 2) ? Wv : Wo;
    u16* dst = Wt + (size_t)mat * 1048576;
    int bx = (b2 & 31) * 32, by = (b2 >> 5) * 32;
    int tx = t & 31, ty = t >> 5;
    #pragma unroll
    for (int i = ty; i < 32; i += 8) tile[i][tx] = W[(size_t)(by + i) * CD + bx + tx];
    __syncthreads();
    #pragma unroll
    for (int i = ty; i < 32; i += 8)
      dst[(size_t)(bx + i) * CD + by + tx] = f2b(tile[tx][i]);
  }
}

// ---------------- GEMM 128x128: C[M,1024-sub] = A[M,K] @ Bt[N,K]^T ----------------
template <typename OT>
__global__ __launch_bounds__(256) void gemm_bt_k(const u16* __restrict__ A,
                                                 const u16* __restrict__ Bt,
                                                 OT* __restrict__ Cout,
                                                 int K, size_t subStride) {
  __shared__ __align__(16) u16 As[128 * 32];
  __shared__ __align__(16) u16 Bs[128 * 32];
  int t = threadIdx.x;
  int lane = t & 63, w = t >> 6;
  int m = lane & 15, quad = lane >> 4;
  int wrow = w >> 1, wcol = w & 1;
  int m0 = blockIdx.y * 128, n0 = blockIdx.x * 128;

  f32x4 acc[4][4];
  #pragma unroll
  for (int i = 0; i < 4; i++)
    #pragma unroll
    for (int j = 0; j < 4; j++) acc[i][j] = (f32x4){0.f, 0.f, 0.f, 0.f};

  for (int k0 = 0; k0 < K; k0 += 32) {
    __syncthreads();
    #pragma unroll
    for (int p = 0; p < 2; p++) {
      int idx = p * 256 + t;
      int row = idx >> 2, c = idx & 3;
      int cc = c ^ (row & 3);
      gload_lds16(A + (size_t)(m0 + row) * K + k0 + cc * 8,
                  As + (size_t)(p * 256 + (t & 192)) * 8);
      gload_lds16(Bt + (size_t)(n0 + row) * K + k0 + cc * 8,
                  Bs + (size_t)(p * 256 + (t & 192)) * 8);
    }
    __syncthreads();
    bf16x8 af[4], bfr[4];
    #pragma unroll
    for (int mt = 0; mt < 4; mt++) {
      int r = wrow * 64 + mt * 16 + m;
      af[mt] = *(const bf16x8*)&As[r * 32 + ((quad ^ (r & 3)) * 8)];
    }
    #pragma unroll
    for (int nt = 0; nt < 4; nt++) {
      int r = wcol * 64 + nt * 16 + m;
      bfr[nt] = *(const bf16x8*)&Bs[r * 32 + ((quad ^ (r & 3)) * 8)];
    }
    #pragma unroll
    for (int mt = 0; mt < 4; mt++)
      #pragma unroll
      for (int nt = 0; nt < 4; nt++)
        acc[mt][nt] = __builtin_amdgcn_mfma_f32_16x16x32_bf16(af[mt], bfr[nt],
                                                              acc[mt][nt], 0, 0, 0);
  }

  #pragma unroll
  for (int mt = 0; mt < 4; mt++) {
    #pragma unroll
    for (int nt = 0; nt < 4; nt++) {
      int c = n0 + wcol * 64 + nt * 16 + m;
      OT* outp = Cout + (size_t)(c >> 10) * subStride + (c & 1023);
      #pragma unroll
      for (int rr = 0; rr < 4; rr++) {
        int r = m0 + wrow * 64 + mt * 16 + quad * 4 + rr;
        store_out(outp + (size_t)r * CD, acc[mt][nt][rr]);
      }
    }
  }
}

// ---------------- GEMM 128x64 (out-proj): more blocks for occupancy ----------------
__global__ __launch_bounds__(256) void gemm_bt64_k(const u16* __restrict__ A,
                                                   const u16* __restrict__ Bt,
                                                   float* __restrict__ Cout, int K) {
  __shared__ __align__(16) u16 As[128 * 32];
  __shared__ __align__(16) u16 Bs[64 * 32];
  int t = threadIdx.x;
  int lane = t & 63, w = t >> 6;
  int m = lane & 15, quad = lane >> 4;
  int wrow = w >> 1, wcol = w & 1;
  int m0 = blockIdx.y * 128, n0 = blockIdx.x * 64;

  f32x4 acc[4][2];
  #pragma unroll
  for (int i = 0; i < 4; i++)
    #pragma unroll
    for (int j = 0; j < 2; j++) acc[i][j] = (f32x4){0.f, 0.f, 0.f, 0.f};

  for (int k0 = 0; k0 < K; k0 += 32) {
    __syncthreads();
    #pragma unroll
    for (int p = 0; p < 2; p++) {
      int idx = p * 256 + t;
      int row = idx >> 2, cc = (idx & 3) ^ (row & 3);
      gload_lds16(A + (size_t)(m0 + row) * K + k0 + cc * 8,
                  As + (size_t)(p * 256 + (t & 192)) * 8);
    }
    {
      int row = t >> 2, cc = (t & 3) ^ (row & 3);
      gload_lds16(Bt + (size_t)(n0 + row) * K + k0 + cc * 8,
                  Bs + (size_t)(t & 192) * 8);
    }
    __syncthreads();
    bf16x8 af[4], bfr[2];
    #pragma unroll
    for (int mt = 0; mt < 4; mt++) {
      int r = wrow * 64 + mt * 16 + m;
      af[mt] = *(const bf16x8*)&As[r * 32 + ((quad ^ (r & 3)) * 8)];
    }
    #pragma unroll
    for (int nt = 0; nt < 2; nt++) {
      int r = wcol * 32 + nt * 16 + m;
      bfr[nt] = *(const bf16x8*)&Bs[r * 32 + ((quad ^ (r & 3)) * 8)];
    }
    #pragma unroll
    for (int mt = 0; mt < 4; mt++)
      #pragma unroll
      for (int nt = 0; nt < 2; nt++)
        acc[mt][nt] = __builtin_amdgcn_mfma_f32_16x16x32_bf16(af[mt], bfr[nt],
                                                              acc[mt][nt], 0, 0, 0);
  }

  #pragma unroll
  for (int mt = 0; mt < 4; mt++) {
    #pragma unroll
    for (int nt = 0; nt < 2; nt++) {
      int c = n0 + wcol * 32 + nt * 16 + m;
      #pragma unroll
      for (int rr = 0; rr < 4; rr++) {
        int r = m0 + wrow * 64 + mt * 16 + quad * 4 + rr;
        Cout[(size_t)r * CD + c] = acc[mt][nt][rr];
      }
    }
  }
}

// ---------------- flash attention, 32x32 MFMA, kv-split x4, no P-LDS ----------------
// grid (T/128, H, B*4): z = b + 2*quarter. 256 threads = 4 waves; wave w owns
// q-rows [w*32, w*32+32). S^T = K*Q^T (col=qrow), O^T = V^T*P^T; P frags built
// in-register via permlane swaps. exp2-domain softmax, no max-shift.
__global__ __launch_bounds__(256, 8) void attn_k(const u16* __restrict__ Qb,
                                                 const u16* __restrict__ Kb,
                                                 const u16* __restrict__ Vb,
                                                 const int* __restrict__ mask,
                                                 u16* __restrict__ Opart,
                                                 float* __restrict__ Lpart) {
  __shared__ __align__(16) u16 Ks[64 * 64];   // swizzled 16B chunks
  __shared__ __align__(16) u32 VsD[64 * 36];  // V^T dword (d,pr) at d*36 + (pr^((d>>3)<<2))

  int t = threadIdx.x, lane = t & 63, w = t >> 6;
  int c32 = lane & 31, hf = lane >> 5;
  int qt = blockIdx.x, head = blockIdx.y;
  int b = blockIdx.z & 1, qtr = blockIdx.z >> 1;
  int kv0 = qtr * 512;
  int gid = (b * 16 + head) * 16 + qt;
  const float EC = 0.18033688f;  // 0.125 * log2(e)

  // Q fragments direct from global (one-time): B-layout col=qrow, k=hf*8+j
  const u16* Qg = Qb + ((size_t)(b * CT + qt * 128 + w * 32 + c32)) * CD + head * CDH;
  bf16x8 qbf[4];
  #pragma unroll
  for (int kc = 0; kc < 4; kc++)
    qbf[kc] = *(const bf16x8*)(Qg + kc * 16 + hf * 8);

  // mask scan over this quarter
  const int* mk = mask + b * CT + kv0;
  int localAny = 0;
  for (int i = t; i < 512; i += 256) localAny |= (mk[i] == 0);
  int anyM = __syncthreads_or(localAny);

  f32x16 oacc[2];
  #pragma unroll
  for (int dt = 0; dt < 2; dt++)
    #pragma unroll
    for (int r = 0; r < 16; r++) oacc[dt][r] = 0.f;
  float lp = 0.f;

  const u16* Kg0 = Kb + ((size_t)(b * CT + kv0)) * CD + head * CDH;
  const u16* Vg0 = Vb + ((size_t)(b * CT + kv0)) * CD + head * CDH;

  // V prefetch (iter 0)
  int vpr = t >> 3, vdg = t & 7;
  const u16* VgT = Vg0 + (size_t)(2 * vpr) * CD + vdg * 8;
  uint4 va = *(const uint4*)VgT;
  uint4 vb2 = *(const uint4*)(VgT + CD);

  for (int kv = 0; kv < 512; kv += 64) {
    __syncthreads();
    // stage K (async DMA, swizzled)
    #pragma unroll
    for (int p = 0; p < 2; p++) {
      int idx = p * 256 + t;
      int row = idx >> 3, cc = (idx & 7) ^ (row & 7);
      gload_lds16(Kg0 + (size_t)(kv + row) * CD + cc * 8,
                  Ks + (size_t)(p * 256 + (t & 192)) * 8);
    }
    // stage V^T from prefetched regs (swizzled writes)
    {
      const u32* pa = (const u32*)&va;
      const u32* pb = (const u32*)&vb2;
      u32* dst = VsD + (size_t)vdg * 288 + (vpr ^ (vdg << 2));
      #pragma unroll
      for (int j = 0; j < 8; j++) {
        u32 lo_dw = pa[j >> 1], hi_dw = pb[j >> 1];
        u32 pkv = (j & 1) ? __builtin_amdgcn_perm(hi_dw, lo_dw, 0x07060302u)
                          : __builtin_amdgcn_perm(hi_dw, lo_dw, 0x05040100u);
        dst[j * 36] = pkv;
      }
    }
    __syncthreads();
    // prefetch next V tile
    if (kv + 64 < 512) {
      VgT = Vg0 + (size_t)(kv + 64 + 2 * vpr) * CD + vdg * 8;
      va = *(const uint4*)VgT;
      vb2 = *(const uint4*)(VgT + CD);
    }

    #pragma unroll
    for (int kt = 0; kt < 2; kt++) {
      // S^T tile: 32 keys x 32 qrows, K-dim 64
      f32x16 sv;
      #pragma unroll
      for (int r = 0; r < 16; r++) sv[r] = 0.f;
      int key = kt * 32 + c32;
      #pragma unroll
      for (int kc = 0; kc < 4; kc++) {
        int ch = kc * 2 + hf;
        bf16x8 af = *(const bf16x8*)&Ks[key * 64 + ((ch ^ (key & 7)) * 8)];
        sv = __builtin_amdgcn_mfma_f32_32x32x16_bf16(af, qbf[kc], sv, 0, 0, 0);
      }
      // softmax in exp2 domain (no max-shift; scores are bounded) + pack
      u32 pk[8];
      #pragma unroll
      for (int i = 0; i < 8; i++) {
        float x0 = sv[2 * i] * EC, x1 = sv[2 * i + 1] * EC;
        if (anyM) {
          int r0 = 2 * i, r1 = 2 * i + 1;
          int mi0 = kv + kt * 32 + (r0 & 3) + 8 * (r0 >> 2) + 4 * hf;
          int mi1 = kv + kt * 32 + (r1 & 3) + 8 * (r1 >> 2) + 4 * hf;
          x0 += mk[mi0] ? 0.f : -1.0e9f;
          x1 += mk[mi1] ? 0.f : -1.0e9f;
        }
        float p0 = fexp2(x0);
        float p1 = fexp2(x1);
        lp += p0 + p1;
        pk[i] = pk2(p0, p1);
      }
      // per 16-key chunk: build P B-frag via half-swaps, then PV MFMAs
      #pragma unroll
      for (int c = 0; c < 2; c++) {
        u32 d0 = pk[4 * c + 0], d2 = pk[4 * c + 2];
        u32 d1 = pk[4 * c + 1], d3 = pk[4 * c + 3];
        plswap(d0, d2, hf);
        plswap(d1, d3, hf);
        union { u32 u[4]; bf16x8 v; } pf;
        pf.u[0] = d0; pf.u[1] = d1; pf.u[2] = d2; pf.u[3] = d3;
        int prb = kt * 16 + c * 8 + hf * 4;
        #pragma unroll
        for (int dt = 0; dt < 2; dt++) {
          int d = dt * 32 + c32;
          const u32* vp = VsD + d * 36 + (prb ^ ((d >> 3) << 2));
          bf16x8 vf = *(const bf16x8*)vp;
          oacc[dt] = __builtin_amdgcn_mfma_f32_32x32x16_bf16(vf, pf.v, oacc[dt], 0, 0, 0);
        }
      }
    }
  }

  // epilogue: reduce l across halves (in-lane rows), normalize, store partial
  float lT = lp + __shfl_xor(lp, 32, 64);
  float linv = 1.f / lT;
  u16* Op = Opart + ((size_t)(qtr * 512 + gid) * 128 + w * 32 + c32) * 64;
  #pragma unroll
  for (int dt = 0; dt < 2; dt++) {
    #pragma unroll
    for (int g = 0; g < 4; g++) {
      float o0 = oacc[dt][4 * g + 0] * linv, o1 = oacc[dt][4 * g + 1] * linv;
      float o2 = oacc[dt][4 * g + 2] * linv, o3 = oacc[dt][4 * g + 3] * linv;
      uint2 pw;
      pw.x = pk2(o0, o1);
      pw.y = pk2(o2, o3);
      *(uint2*)(Op + dt * 32 + 8 * g + 4 * hf) = pw;
    }
  }
  if (lane < 32) Lpart[(size_t)(qtr * 512 + gid) * 128 + w * 32 + lane] = lT;
}

// ---------------- combine kv-split partials (4-way) ----------------
__global__ __launch_bounds__(256) void combine_k(const u16* __restrict__ Opart,
                                                 const float* __restrict__ Lpart,
                                                 u16* __restrict__ Ob) {
  int fid = blockIdx.x * 256 + threadIdx.x;  // 1M threads, 4 elems each
  int gid = fid >> 11;
  int rem = fid & 2047;
  int r = rem >> 4, d = (rem & 15) * 4;
  int b = gid >> 8, head = (gid >> 4) & 15, qt = gid & 15;
  float l[4], lsum = 0.f;
  uint2 A[4];
  #pragma unroll
  for (int q = 0; q < 4; q++) {
    size_t idx = (size_t)(q * 512 + gid) * 128 + r;
    l[q] = Lpart[idx];
    A[q] = *(const uint2*)(Opart + idx * 64 + d);
    lsum += l[q];
  }
  float inv = 1.f / lsum;
  float o0 = 0.f, o1 = 0.f, o2 = 0.f, o3 = 0.f;
  #pragma unroll
  for (int q = 0; q < 4; q++) {
    float wq = l[q] * inv;
    o0 += wq * b2f(A[q].x & 0xffffu);
    o1 += wq * b2f(A[q].x >> 16);
    o2 += wq * b2f(A[q].y & 0xffffu);
    o3 += wq * b2f(A[q].y >> 16);
  }
  uint2 pw;
  pw.x = pk2(o0, o1);
  pw.y = pk2(o2, o3);
  size_t trow = (size_t)b * CT + qt * 128 + r;
  *(uint2*)(Ob + trow * CD + head * CDH + d) = pw;
}

extern "C" void kernel_launch(void* const* d_in, const int* in_sizes, int n_in,
                              void* d_out, int out_size, void* d_ws, size_t ws_size,
                              hipStream_t stream) {
  const float* x  = (const float*)d_in[0];
  const int* mask = (const int*)d_in[1];
  const float* Wq = (const float*)d_in[2];
  const float* Wk = (const float*)d_in[3];
  const float* Wv = (const float*)d_in[4];
  const float* Wo = (const float*)d_in[5];
  float* out = (float*)d_out;

  u16* Xb    = (u16*)d_ws;                         // [4096][1024]
  u16* Wqkv  = Xb + (size_t)4096 * 1024;           // Wq^T|Wk^T|Wv^T|Wo^T [4096][1024]
  u16* WoT   = Wqkv + (size_t)3072 * 1024;
  u16* Qb    = Wqkv + (size_t)4096 * 1024;         // Q,K,V each [4096][1024]
  u16* Ob    = Qb + (size_t)3 * 4096 * 1024;       // attn out [4096][1024]
  u16* Opart = Ob + (size_t)4096 * 1024;           // [4*512][128][64] bf16
  float* Lpart = (float*)(Opart + (size_t)4 * 512 * 128 * 64);  // [4*512][128]

  prep_k<<<8192, 256, 0, stream>>>(x, Wq, Wk, Wv, Wo, Xb, Wqkv);
  gemm_bt_k<u16><<<dim3(24, 32), 256, 0, stream>>>(Xb, Wqkv, Qb, 1024,
                                                   (size_t)4096 * 1024);
  attn_k<<<dim3(16, 16, 8), 256, 0, stream>>>(Qb, Qb + (size_t)4096 * 1024,
                                              Qb + (size_t)2 * 4096 * 1024, mask,
                                              Opart, Lpart);
  combine_k<<<4096, 256, 0, stream>>>(Opart, Lpart, Ob);
  gemm_bt64_k<<<dim3(16, 32), 256, 0, stream>>>(Ob, WoT, out, 1024);
}

// Round 6
// 211.071 us; speedup vs baseline: 2.1912x; 2.1912x over previous
//
#include <hip/hip_runtime.h>
#include <stdint.h>

typedef unsigned short u16;
typedef unsigned int u32;

constexpr int CB = 2, CT = 2048, CH = 16, CDH = 64, CD = 1024;

typedef __attribute__((ext_vector_type(8))) short bf16x8;
typedef __attribute__((ext_vector_type(4))) float f32x4;
typedef __attribute__((ext_vector_type(16))) float f32x16;

typedef __attribute__((address_space(1))) const u32 as1_cu32;
typedef __attribute__((address_space(3))) u32 as3_u32;

__device__ __forceinline__ void gload_lds16(const void* g, void* l) {
  __builtin_amdgcn_global_load_lds((as1_cu32*)g, (as3_u32*)l, 16, 0, 0);
}

// fp32 -> bf16 round-to-nearest-even (finite inputs only)
__device__ __forceinline__ u16 f2b(float f) {
  u32 x = __float_as_uint(f);
  u32 r = (x + 0x7fffu + ((x >> 16) & 1u)) >> 16;
  return (u16)r;
}

#if __has_builtin(__builtin_amdgcn_cvt_pk_bf16_f32)
typedef __attribute__((ext_vector_type(2))) __bf16 v2bf;
__device__ __forceinline__ u32 pk2(float a, float b) {
  v2bf r = __builtin_amdgcn_cvt_pk_bf16_f32(a, b);
  union { v2bf v; u32 u; } cv; cv.v = r; return cv.u;
}
#else
__device__ __forceinline__ u32 pk2(float a, float b) {
  return (u32)f2b(a) | ((u32)f2b(b) << 16);
}
#endif

__device__ __forceinline__ float b2f(u32 lo16) { return __uint_as_float(lo16 << 16); }

// exp2 (v_exp_f32 is natively base-2)
__device__ __forceinline__ float fexp2(float x) {
#if __has_builtin(__builtin_amdgcn_exp2f)
  return __builtin_amdgcn_exp2f(x);
#else
  return __expf(x * 0.69314718056f);
#endif
}

__device__ __forceinline__ void store_out(u16* p, float v) { *p = f2b(v); }
__device__ __forceinline__ void store_out(float* p, float v) { *p = v; }

// half-swap: a' = {a.lo32lanes, b.lo32lanes}, b' = {a.hi, b.hi}
#if __has_builtin(__builtin_amdgcn_permlane32_swap)
__device__ __forceinline__ void plswap(u32& a, u32& b, int) {
  auto r = __builtin_amdgcn_permlane32_swap(a, b, false, false);
  a = (u32)r[0]; b = (u32)r[1];
}
#else
__device__ __forceinline__ void plswap(u32& a, u32& b, int hf) {
  u32 ta = (u32)__shfl_xor((int)a, 32, 64);
  u32 tb = (u32)__shfl_xor((int)b, 32, 64);
  u32 na = hf ? tb : a;
  u32 nb = hf ? b : ta;
  a = na; b = nb;
}
#endif

// ---------------- fused prep: cast x + transpose/cast 4 weight mats ----------------
__global__ __launch_bounds__(256) void prep_k(const float* __restrict__ x,
                                              const float* __restrict__ Wq,
                                              const float* __restrict__ Wk,
                                              const float* __restrict__ Wv,
                                              const float* __restrict__ Wo,
                                              u16* __restrict__ Xb,
                                              u16* __restrict__ Wt) {
  __shared__ float tile[32][33];
  int bid = blockIdx.x, t = threadIdx.x;
  if (bid < 4096) {
    int i = bid * 256 + t;
    float4 v = ((const float4*)x)[i];
    ushort4 r;
    r.x = f2b(v.x); r.y = f2b(v.y); r.z = f2b(v.z); r.w = f2b(v.w);
    ((ushort4*)Xb)[i] = r;
  } else {
    int tid2 = bid - 4096;
    int mat = tid2 >> 10, b2 = tid2 & 1023;
    const float* W = (mat == 0) ? Wq : (mat == 1) ? Wk : (mat == 2) ? Wv : Wo;
    u16* dst = Wt + (size_t)mat * 1048576;
    int bx = (b2 & 31) * 32, by = (b2 >> 5) * 32;
    int tx = t & 31, ty = t >> 5;
    #pragma unroll
    for (int i = ty; i < 32; i += 8) tile[i][tx] = W[(size_t)(by + i) * CD + bx + tx];
    __syncthreads();
    #pragma unroll
    for (int i = ty; i < 32; i += 8)
      dst[(size_t)(bx + i) * CD + by + tx] = f2b(tile[tx][i]);
  }
}

// ---------------- GEMM 128x128: C[M,1024-sub] = A[M,K] @ Bt[N,K]^T ----------------
template <typename OT>
__global__ __launch_bounds__(256) void gemm_bt_k(const u16* __restrict__ A,
                                                 const u16* __restrict__ Bt,
                                                 OT* __restrict__ Cout,
                                                 int K, size_t subStride) {
  __shared__ __align__(16) u16 As[128 * 32];
  __shared__ __align__(16) u16 Bs[128 * 32];
  int t = threadIdx.x;
  int lane = t & 63, w = t >> 6;
  int m = lane & 15, quad = lane >> 4;
  int wrow = w >> 1, wcol = w & 1;
  int m0 = blockIdx.y * 128, n0 = blockIdx.x * 128;

  f32x4 acc[4][4];
  #pragma unroll
  for (int i = 0; i < 4; i++)
    #pragma unroll
    for (int j = 0; j < 4; j++) acc[i][j] = (f32x4){0.f, 0.f, 0.f, 0.f};

  for (int k0 = 0; k0 < K; k0 += 32) {
    __syncthreads();
    #pragma unroll
    for (int p = 0; p < 2; p++) {
      int idx = p * 256 + t;
      int row = idx >> 2, c = idx & 3;
      int cc = c ^ (row & 3);
      gload_lds16(A + (size_t)(m0 + row) * K + k0 + cc * 8,
                  As + (size_t)(p * 256 + (t & 192)) * 8);
      gload_lds16(Bt + (size_t)(n0 + row) * K + k0 + cc * 8,
                  Bs + (size_t)(p * 256 + (t & 192)) * 8);
    }
    __syncthreads();
    bf16x8 af[4], bfr[4];
    #pragma unroll
    for (int mt = 0; mt < 4; mt++) {
      int r = wrow * 64 + mt * 16 + m;
      af[mt] = *(const bf16x8*)&As[r * 32 + ((quad ^ (r & 3)) * 8)];
    }
    #pragma unroll
    for (int nt = 0; nt < 4; nt++) {
      int r = wcol * 64 + nt * 16 + m;
      bfr[nt] = *(const bf16x8*)&Bs[r * 32 + ((quad ^ (r & 3)) * 8)];
    }
    #pragma unroll
    for (int mt = 0; mt < 4; mt++)
      #pragma unroll
      for (int nt = 0; nt < 4; nt++)
        acc[mt][nt] = __builtin_amdgcn_mfma_f32_16x16x32_bf16(af[mt], bfr[nt],
                                                              acc[mt][nt], 0, 0, 0);
  }

  #pragma unroll
  for (int mt = 0; mt < 4; mt++) {
    #pragma unroll
    for (int nt = 0; nt < 4; nt++) {
      int c = n0 + wcol * 64 + nt * 16 + m;
      OT* outp = Cout + (size_t)(c >> 10) * subStride + (c & 1023);
      #pragma unroll
      for (int rr = 0; rr < 4; rr++) {
        int r = m0 + wrow * 64 + mt * 16 + quad * 4 + rr;
        store_out(outp + (size_t)r * CD, acc[mt][nt][rr]);
      }
    }
  }
}

// ---------------- GEMM 128x64 (out-proj): more blocks for occupancy ----------------
__global__ __launch_bounds__(256) void gemm_bt64_k(const u16* __restrict__ A,
                                                   const u16* __restrict__ Bt,
                                                   float* __restrict__ Cout, int K) {
  __shared__ __align__(16) u16 As[128 * 32];
  __shared__ __align__(16) u16 Bs[64 * 32];
  int t = threadIdx.x;
  int lane = t & 63, w = t >> 6;
  int m = lane & 15, quad = lane >> 4;
  int wrow = w >> 1, wcol = w & 1;
  int m0 = blockIdx.y * 128, n0 = blockIdx.x * 64;

  f32x4 acc[4][2];
  #pragma unroll
  for (int i = 0; i < 4; i++)
    #pragma unroll
    for (int j = 0; j < 2; j++) acc[i][j] = (f32x4){0.f, 0.f, 0.f, 0.f};

  for (int k0 = 0; k0 < K; k0 += 32) {
    __syncthreads();
    #pragma unroll
    for (int p = 0; p < 2; p++) {
      int idx = p * 256 + t;
      int row = idx >> 2, cc = (idx & 3) ^ (row & 3);
      gload_lds16(A + (size_t)(m0 + row) * K + k0 + cc * 8,
                  As + (size_t)(p * 256 + (t & 192)) * 8);
    }
    {
      int row = t >> 2, cc = (t & 3) ^ (row & 3);
      gload_lds16(Bt + (size_t)(n0 + row) * K + k0 + cc * 8,
                  Bs + (size_t)(t & 192) * 8);
    }
    __syncthreads();
    bf16x8 af[4], bfr[2];
    #pragma unroll
    for (int mt = 0; mt < 4; mt++) {
      int r = wrow * 64 + mt * 16 + m;
      af[mt] = *(const bf16x8*)&As[r * 32 + ((quad ^ (r & 3)) * 8)];
    }
    #pragma unroll
    for (int nt = 0; nt < 2; nt++) {
      int r = wcol * 32 + nt * 16 + m;
      bfr[nt] = *(const bf16x8*)&Bs[r * 32 + ((quad ^ (r & 3)) * 8)];
    }
    #pragma unroll
    for (int mt = 0; mt < 4; mt++)
      #pragma unroll
      for (int nt = 0; nt < 2; nt++)
        acc[mt][nt] = __builtin_amdgcn_mfma_f32_16x16x32_bf16(af[mt], bfr[nt],
                                                              acc[mt][nt], 0, 0, 0);
  }

  #pragma unroll
  for (int mt = 0; mt < 4; mt++) {
    #pragma unroll
    for (int nt = 0; nt < 2; nt++) {
      int c = n0 + wcol * 32 + nt * 16 + m;
      #pragma unroll
      for (int rr = 0; rr < 4; rr++) {
        int r = m0 + wrow * 64 + mt * 16 + quad * 4 + rr;
        Cout[(size_t)r * CD + c] = acc[mt][nt][rr];
      }
    }
  }
}

// ---------------- flash attention, 32x32 MFMA, kv-split x4, no P-LDS ----------------
// grid (T/128, H, B*4): z = b + 2*quarter. 256 threads = 4 waves; wave w owns
// q-rows [w*32, w*32+32). S^T = K*Q^T (col=qrow), O^T = V^T*P^T; P frags built
// in-register via permlane swaps. exp2-domain softmax, no max-shift.
// launch_bounds min-waves=4 (VGPR<=128): (256,8) forced VGPR=32 -> spill storm
// (r5: 1.28 GB scratch traffic). Compiler lands at ~64 VGPR naturally.
__global__ __launch_bounds__(256, 4) void attn_k(const u16* __restrict__ Qb,
                                                 const u16* __restrict__ Kb,
                                                 const u16* __restrict__ Vb,
                                                 const int* __restrict__ mask,
                                                 u16* __restrict__ Opart,
                                                 float* __restrict__ Lpart) {
  __shared__ __align__(16) u16 Ks[64 * 64];   // swizzled 16B chunks
  __shared__ __align__(16) u32 VsD[64 * 36];  // V^T dword (d,pr) at d*36 + (pr^((d>>3)<<2))

  int t = threadIdx.x, lane = t & 63, w = t >> 6;
  int c32 = lane & 31, hf = lane >> 5;
  int qt = blockIdx.x, head = blockIdx.y;
  int b = blockIdx.z & 1, qtr = blockIdx.z >> 1;
  int kv0 = qtr * 512;
  int gid = (b * 16 + head) * 16 + qt;
  const float EC = 0.18033688f;  // 0.125 * log2(e)

  // Q fragments direct from global (one-time): B-layout col=qrow, k=hf*8+j
  const u16* Qg = Qb + ((size_t)(b * CT + qt * 128 + w * 32 + c32)) * CD + head * CDH;
  bf16x8 qbf[4];
  #pragma unroll
  for (int kc = 0; kc < 4; kc++)
    qbf[kc] = *(const bf16x8*)(Qg + kc * 16 + hf * 8);

  // mask scan over this quarter
  const int* mk = mask + b * CT + kv0;
  int localAny = 0;
  for (int i = t; i < 512; i += 256) localAny |= (mk[i] == 0);
  int anyM = __syncthreads_or(localAny);

  f32x16 oacc[2];
  #pragma unroll
  for (int dt = 0; dt < 2; dt++)
    #pragma unroll
    for (int r = 0; r < 16; r++) oacc[dt][r] = 0.f;
  float lp = 0.f;

  const u16* Kg0 = Kb + ((size_t)(b * CT + kv0)) * CD + head * CDH;
  const u16* Vg0 = Vb + ((size_t)(b * CT + kv0)) * CD + head * CDH;

  // V prefetch (iter 0)
  int vpr = t >> 3, vdg = t & 7;
  const u16* VgT = Vg0 + (size_t)(2 * vpr) * CD + vdg * 8;
  uint4 va = *(const uint4*)VgT;
  uint4 vb2 = *(const uint4*)(VgT + CD);

  for (int kv = 0; kv < 512; kv += 64) {
    __syncthreads();
    // stage K (async DMA, swizzled)
    #pragma unroll
    for (int p = 0; p < 2; p++) {
      int idx = p * 256 + t;
      int row = idx >> 3, cc = (idx & 7) ^ (row & 7);
      gload_lds16(Kg0 + (size_t)(kv + row) * CD + cc * 8,
                  Ks + (size_t)(p * 256 + (t & 192)) * 8);
    }
    // stage V^T from prefetched regs (swizzled writes)
    {
      const u32* pa = (const u32*)&va;
      const u32* pb = (const u32*)&vb2;
      u32* dst = VsD + (size_t)vdg * 288 + (vpr ^ (vdg << 2));
      #pragma unroll
      for (int j = 0; j < 8; j++) {
        u32 lo_dw = pa[j >> 1], hi_dw = pb[j >> 1];
        u32 pkv = (j & 1) ? __builtin_amdgcn_perm(hi_dw, lo_dw, 0x07060302u)
                          : __builtin_amdgcn_perm(hi_dw, lo_dw, 0x05040100u);
        dst[j * 36] = pkv;
      }
    }
    __syncthreads();
    // prefetch next V tile
    if (kv + 64 < 512) {
      VgT = Vg0 + (size_t)(kv + 64 + 2 * vpr) * CD + vdg * 8;
      va = *(const uint4*)VgT;
      vb2 = *(const uint4*)(VgT + CD);
    }

    #pragma unroll
    for (int kt = 0; kt < 2; kt++) {
      // S^T tile: 32 keys x 32 qrows, K-dim 64
      f32x16 sv;
      #pragma unroll
      for (int r = 0; r < 16; r++) sv[r] = 0.f;
      int key = kt * 32 + c32;
      #pragma unroll
      for (int kc = 0; kc < 4; kc++) {
        int ch = kc * 2 + hf;
        bf16x8 af = *(const bf16x8*)&Ks[key * 64 + ((ch ^ (key & 7)) * 8)];
        sv = __builtin_amdgcn_mfma_f32_32x32x16_bf16(af, qbf[kc], sv, 0, 0, 0);
      }
      // softmax in exp2 domain (no max-shift; scores are bounded) + pack
      u32 pk[8];
      #pragma unroll
      for (int i = 0; i < 8; i++) {
        float x0 = sv[2 * i] * EC, x1 = sv[2 * i + 1] * EC;
        if (anyM) {
          int r0 = 2 * i, r1 = 2 * i + 1;
          int mi0 = kv + kt * 32 + (r0 & 3) + 8 * (r0 >> 2) + 4 * hf;
          int mi1 = kv + kt * 32 + (r1 & 3) + 8 * (r1 >> 2) + 4 * hf;
          x0 += mk[mi0] ? 0.f : -1.0e9f;
          x1 += mk[mi1] ? 0.f : -1.0e9f;
        }
        float p0 = fexp2(x0);
        float p1 = fexp2(x1);
        lp += p0 + p1;
        pk[i] = pk2(p0, p1);
      }
      // per 16-key chunk: build P B-frag via half-swaps, then PV MFMAs
      #pragma unroll
      for (int c = 0; c < 2; c++) {
        u32 d0 = pk[4 * c + 0], d2 = pk[4 * c + 2];
        u32 d1 = pk[4 * c + 1], d3 = pk[4 * c + 3];
        plswap(d0, d2, hf);
        plswap(d1, d3, hf);
        union { u32 u[4]; bf16x8 v; } pf;
        pf.u[0] = d0; pf.u[1] = d1; pf.u[2] = d2; pf.u[3] = d3;
        int prb = kt * 16 + c * 8 + hf * 4;
        #pragma unroll
        for (int dt = 0; dt < 2; dt++) {
          int d = dt * 32 + c32;
          const u32* vp = VsD + d * 36 + (prb ^ ((d >> 3) << 2));
          bf16x8 vf = *(const bf16x8*)vp;
          oacc[dt] = __builtin_amdgcn_mfma_f32_32x32x16_bf16(vf, pf.v, oacc[dt], 0, 0, 0);
        }
      }
    }
  }

  // epilogue: reduce l across halves (in-lane rows), normalize, store partial
  float lT = lp + __shfl_xor(lp, 32, 64);
  float linv = 1.f / lT;
  u16* Op = Opart + ((size_t)(qtr * 512 + gid) * 128 + w * 32 + c32) * 64;
  #pragma unroll
  for (int dt = 0; dt < 2; dt++) {
    #pragma unroll
    for (int g = 0; g < 4; g++) {
      float o0 = oacc[dt][4 * g + 0] * linv, o1 = oacc[dt][4 * g + 1] * linv;
      float o2 = oacc[dt][4 * g + 2] * linv, o3 = oacc[dt][4 * g + 3] * linv;
      uint2 pw;
      pw.x = pk2(o0, o1);
      pw.y = pk2(o2, o3);
      *(uint2*)(Op + dt * 32 + 8 * g + 4 * hf) = pw;
    }
  }
  if (lane < 32) Lpart[(size_t)(qtr * 512 + gid) * 128 + w * 32 + lane] = lT;
}

// ---------------- combine kv-split partials (4-way) ----------------
__global__ __launch_bounds__(256) void combine_k(const u16* __restrict__ Opart,
                                                 const float* __restrict__ Lpart,
                                                 u16* __restrict__ Ob) {
  int fid = blockIdx.x * 256 + threadIdx.x;  // 1M threads, 4 elems each
  int gid = fid >> 11;
  int rem = fid & 2047;
  int r = rem >> 4, d = (rem & 15) * 4;
  int b = gid >> 8, head = (gid >> 4) & 15, qt = gid & 15;
  float l[4], lsum = 0.f;
  uint2 A[4];
  #pragma unroll
  for (int q = 0; q < 4; q++) {
    size_t idx = (size_t)(q * 512 + gid) * 128 + r;
    l[q] = Lpart[idx];
    A[q] = *(const uint2*)(Opart + idx * 64 + d);
    lsum += l[q];
  }
  float inv = 1.f / lsum;
  float o0 = 0.f, o1 = 0.f, o2 = 0.f, o3 = 0.f;
  #pragma unroll
  for (int q = 0; q < 4; q++) {
    float wq = l[q] * inv;
    o0 += wq * b2f(A[q].x & 0xffffu);
    o1 += wq * b2f(A[q].x >> 16);
    o2 += wq * b2f(A[q].y & 0xffffu);
    o3 += wq * b2f(A[q].y >> 16);
  }
  uint2 pw;
  pw.x = pk2(o0, o1);
  pw.y = pk2(o2, o3);
  size_t trow = (size_t)b * CT + qt * 128 + r;
  *(uint2*)(Ob + trow * CD + head * CDH + d) = pw;
}

extern "C" void kernel_launch(void* const* d_in, const int* in_sizes, int n_in,
                              void* d_out, int out_size, void* d_ws, size_t ws_size,
                              hipStream_t stream) {
  const float* x  = (const float*)d_in[0];
  const int* mask = (const int*)d_in[1];
  const float* Wq = (const float*)d_in[2];
  const float* Wk = (const float*)d_in[3];
  const float* Wv = (const float*)d_in[4];
  const float* Wo = (const float*)d_in[5];
  float* out = (float*)d_out;

  u16* Xb    = (u16*)d_ws;                         // [4096][1024]
  u16* Wqkv  = Xb + (size_t)4096 * 1024;           // Wq^T|Wk^T|Wv^T|Wo^T [4096][1024]
  u16* WoT   = Wqkv + (size_t)3072 * 1024;
  u16* Qb    = Wqkv + (size_t)4096 * 1024;         // Q,K,V each [4096][1024]
  u16* Ob    = Qb + (size_t)3 * 4096 * 1024;       // attn out [4096][1024]
  u16* Opart = Ob + (size_t)4096 * 1024;           // [4*512][128][64] bf16
  float* Lpart = (float*)(Opart + (size_t)4 * 512 * 128 * 64);  // [4*512][128]

  prep_k<<<8192, 256, 0, stream>>>(x, Wq, Wk, Wv, Wo, Xb, Wqkv);
  gemm_bt_k<u16><<<dim3(24, 32), 256, 0, stream>>>(Xb, Wqkv, Qb, 1024,
                                                   (size_t)4096 * 1024);
  attn_k<<<dim3(16, 16, 8), 256, 0, stream>>>(Qb, Qb + (size_t)4096 * 1024,
                                              Qb + (size_t)2 * 4096 * 1024, mask,
                                              Opart, Lpart);
  combine_k<<<4096, 256, 0, stream>>>(Opart, Lpart, Ob);
  gemm_bt64_k<<<dim3(16, 32), 256, 0, stream>>>(Ob, WoT, out, 1024);
}

// Round 7
// 205.631 us; speedup vs baseline: 2.2491x; 1.0265x over previous
//
#include <hip/hip_runtime.h>
#include <stdint.h>

typedef unsigned short u16;
typedef unsigned int u32;

constexpr int CB = 2, CT = 2048, CH = 16, CDH = 64, CD = 1024;

typedef __attribute__((ext_vector_type(8))) short bf16x8;
typedef __attribute__((ext_vector_type(4))) float f32x4;
typedef __attribute__((ext_vector_type(16))) float f32x16;

typedef __attribute__((address_space(1))) const u32 as1_cu32;
typedef __attribute__((address_space(3))) u32 as3_u32;

__device__ __forceinline__ void gload_lds16(const void* g, void* l) {
  __builtin_amdgcn_global_load_lds((as1_cu32*)g, (as3_u32*)l, 16, 0, 0);
}

// fp32 -> bf16 round-to-nearest-even (finite inputs only)
__device__ __forceinline__ u16 f2b(float f) {
  u32 x = __float_as_uint(f);
  u32 r = (x + 0x7fffu + ((x >> 16) & 1u)) >> 16;
  return (u16)r;
}

#if __has_builtin(__builtin_amdgcn_cvt_pk_bf16_f32)
typedef __attribute__((ext_vector_type(2))) __bf16 v2bf;
__device__ __forceinline__ u32 pk2(float a, float b) {
  v2bf r = __builtin_amdgcn_cvt_pk_bf16_f32(a, b);
  union { v2bf v; u32 u; } cv; cv.v = r; return cv.u;
}
#else
__device__ __forceinline__ u32 pk2(float a, float b) {
  return (u32)f2b(a) | ((u32)f2b(b) << 16);
}
#endif

__device__ __forceinline__ float b2f(u32 lo16) { return __uint_as_float(lo16 << 16); }

// exp2 (v_exp_f32 is natively base-2)
__device__ __forceinline__ float fexp2(float x) {
#if __has_builtin(__builtin_amdgcn_exp2f)
  return __builtin_amdgcn_exp2f(x);
#else
  return __expf(x * 0.69314718056f);
#endif
}

__device__ __forceinline__ void store_out(u16* p, float v) { *p = f2b(v); }
__device__ __forceinline__ void store_out(float* p, float v) { *p = v; }

// half-swap: a' = {a.lo32lanes, b.lo32lanes}, b' = {a.hi, b.hi}
#if __has_builtin(__builtin_amdgcn_permlane32_swap)
__device__ __forceinline__ void plswap(u32& a, u32& b, int) {
  auto r = __builtin_amdgcn_permlane32_swap(a, b, false, false);
  a = (u32)r[0]; b = (u32)r[1];
}
#else
__device__ __forceinline__ void plswap(u32& a, u32& b, int hf) {
  u32 ta = (u32)__shfl_xor((int)a, 32, 64);
  u32 tb = (u32)__shfl_xor((int)b, 32, 64);
  u32 na = hf ? tb : a;
  u32 nb = hf ? b : ta;
  a = na; b = nb;
}
#endif

// ---------------- fused prep: cast x + transpose/cast 4 weight mats ----------------
__global__ __launch_bounds__(256) void prep_k(const float* __restrict__ x,
                                              const float* __restrict__ Wq,
                                              const float* __restrict__ Wk,
                                              const float* __restrict__ Wv,
                                              const float* __restrict__ Wo,
                                              u16* __restrict__ Xb,
                                              u16* __restrict__ Wt) {
  __shared__ float tile[32][33];
  int bid = blockIdx.x, t = threadIdx.x;
  if (bid < 4096) {
    int i = bid * 256 + t;
    float4 v = ((const float4*)x)[i];
    ushort4 r;
    r.x = f2b(v.x); r.y = f2b(v.y); r.z = f2b(v.z); r.w = f2b(v.w);
    ((ushort4*)Xb)[i] = r;
  } else {
    int tid2 = bid - 4096;
    int mat = tid2 >> 10, b2 = tid2 & 1023;
    const float* W = (mat == 0) ? Wq : (mat == 1) ? Wk : (mat == 2) ? Wv : Wo;
    u16* dst = Wt + (size_t)mat * 1048576;
    int bx = (b2 & 31) * 32, by = (b2 >> 5) * 32;
    int tx = t & 31, ty = t >> 5;
    #pragma unroll
    for (int i = ty; i < 32; i += 8) tile[i][tx] = W[(size_t)(by + i) * CD + bx + tx];
    __syncthreads();
    #pragma unroll
    for (int i = ty; i < 32; i += 8)
      dst[(size_t)(bx + i) * CD + by + tx] = f2b(tile[tx][i]);
  }
}

// ---------------- GEMM 128x128, BK=64: C = A[M,K] @ Bt[N,K]^T ----------------
// BK=64 halves barrier count vs BK=32 (K=1024 -> 16 iters); LDS 32KB.
// scaleQ applied to output columns with c>>10 == 0 (the Q sub-matrix).
template <typename OT>
__global__ __launch_bounds__(256) void gemm_bt_k(const u16* __restrict__ A,
                                                 const u16* __restrict__ Bt,
                                                 OT* __restrict__ Cout,
                                                 int K, size_t subStride,
                                                 float scaleQ) {
  __shared__ __align__(16) u16 As[128 * 64];
  __shared__ __align__(16) u16 Bs[128 * 64];
  int t = threadIdx.x;
  int lane = t & 63, w = t >> 6;
  int m = lane & 15, quad = lane >> 4;
  int wrow = w >> 1, wcol = w & 1;
  int m0 = blockIdx.y * 128, n0 = blockIdx.x * 128;

  f32x4 acc[4][4];
  #pragma unroll
  for (int i = 0; i < 4; i++)
    #pragma unroll
    for (int j = 0; j < 4; j++) acc[i][j] = (f32x4){0.f, 0.f, 0.f, 0.f};

  for (int k0 = 0; k0 < K; k0 += 64) {
    __syncthreads();
    #pragma unroll
    for (int p = 0; p < 4; p++) {
      int idx = p * 256 + t;
      int row = idx >> 3, cc = (idx & 7) ^ (row & 7);
      gload_lds16(A + (size_t)(m0 + row) * K + k0 + cc * 8,
                  As + (size_t)(p * 256 + (t & 192)) * 8);
      gload_lds16(Bt + (size_t)(n0 + row) * K + k0 + cc * 8,
                  Bs + (size_t)(p * 256 + (t & 192)) * 8);
    }
    __syncthreads();
    #pragma unroll
    for (int kk = 0; kk < 2; kk++) {
      bf16x8 af[4], bfr[4];
      #pragma unroll
      for (int mt = 0; mt < 4; mt++) {
        int r = wrow * 64 + mt * 16 + m;
        af[mt] = *(const bf16x8*)&As[r * 64 + (((kk * 4 + quad) ^ (r & 7)) * 8)];
      }
      #pragma unroll
      for (int nt = 0; nt < 4; nt++) {
        int r = wcol * 64 + nt * 16 + m;
        bfr[nt] = *(const bf16x8*)&Bs[r * 64 + (((kk * 4 + quad) ^ (r & 7)) * 8)];
      }
      #pragma unroll
      for (int mt = 0; mt < 4; mt++)
        #pragma unroll
        for (int nt = 0; nt < 4; nt++)
          acc[mt][nt] = __builtin_amdgcn_mfma_f32_16x16x32_bf16(af[mt], bfr[nt],
                                                                acc[mt][nt], 0, 0, 0);
    }
  }

  #pragma unroll
  for (int mt = 0; mt < 4; mt++) {
    #pragma unroll
    for (int nt = 0; nt < 4; nt++) {
      int c = n0 + wcol * 64 + nt * 16 + m;
      float s = ((c >> 10) == 0) ? scaleQ : 1.0f;
      OT* outp = Cout + (size_t)(c >> 10) * subStride + (c & 1023);
      #pragma unroll
      for (int rr = 0; rr < 4; rr++) {
        int r = m0 + wrow * 64 + mt * 16 + quad * 4 + rr;
        store_out(outp + (size_t)r * CD, acc[mt][nt][rr] * s);
      }
    }
  }
}

// ---------------- GEMM 128x64, BK=64 (out-proj) ----------------
__global__ __launch_bounds__(256) void gemm_bt64_k(const u16* __restrict__ A,
                                                   const u16* __restrict__ Bt,
                                                   float* __restrict__ Cout, int K) {
  __shared__ __align__(16) u16 As[128 * 64];
  __shared__ __align__(16) u16 Bs[64 * 64];
  int t = threadIdx.x;
  int lane = t & 63, w = t >> 6;
  int m = lane & 15, quad = lane >> 4;
  int wrow = w >> 1, wcol = w & 1;
  int m0 = blockIdx.y * 128, n0 = blockIdx.x * 64;

  f32x4 acc[4][2];
  #pragma unroll
  for (int i = 0; i < 4; i++)
    #pragma unroll
    for (int j = 0; j < 2; j++) acc[i][j] = (f32x4){0.f, 0.f, 0.f, 0.f};

  for (int k0 = 0; k0 < K; k0 += 64) {
    __syncthreads();
    #pragma unroll
    for (int p = 0; p < 4; p++) {
      int idx = p * 256 + t;
      int row = idx >> 3, cc = (idx & 7) ^ (row & 7);
      gload_lds16(A + (size_t)(m0 + row) * K + k0 + cc * 8,
                  As + (size_t)(p * 256 + (t & 192)) * 8);
    }
    #pragma unroll
    for (int p = 0; p < 2; p++) {
      int idx = p * 256 + t;
      int row = idx >> 3, cc = (idx & 7) ^ (row & 7);
      gload_lds16(Bt + (size_t)(n0 + row) * K + k0 + cc * 8,
                  Bs + (size_t)(p * 256 + (t & 192)) * 8);
    }
    __syncthreads();
    #pragma unroll
    for (int kk = 0; kk < 2; kk++) {
      bf16x8 af[4], bfr[2];
      #pragma unroll
      for (int mt = 0; mt < 4; mt++) {
        int r = wrow * 64 + mt * 16 + m;
        af[mt] = *(const bf16x8*)&As[r * 64 + (((kk * 4 + quad) ^ (r & 7)) * 8)];
      }
      #pragma unroll
      for (int nt = 0; nt < 2; nt++) {
        int r = wcol * 32 + nt * 16 + m;
        bfr[nt] = *(const bf16x8*)&Bs[r * 64 + (((kk * 4 + quad) ^ (r & 7)) * 8)];
      }
      #pragma unroll
      for (int mt = 0; mt < 4; mt++)
        #pragma unroll
        for (int nt = 0; nt < 2; nt++)
          acc[mt][nt] = __builtin_amdgcn_mfma_f32_16x16x32_bf16(af[mt], bfr[nt],
                                                                acc[mt][nt], 0, 0, 0);
    }
  }

  #pragma unroll
  for (int mt = 0; mt < 4; mt++) {
    #pragma unroll
    for (int nt = 0; nt < 2; nt++) {
      int c = n0 + wcol * 32 + nt * 16 + m;
      #pragma unroll
      for (int rr = 0; rr < 4; rr++) {
        int r = m0 + wrow * 64 + mt * 16 + quad * 4 + rr;
        Cout[(size_t)r * CD + c] = acc[mt][nt][rr];
      }
    }
  }
}

// ---------------- flash attention, 32x32 MFMA, kv-split x4, no P-LDS ----------------
// Q is pre-scaled by 0.125*log2(e) in the QKV GEMM epilogue, so S accumulates
// directly in the exp2 domain. (256,4): (256,8) forced VGPR=32 -> spill storm (r5).
__global__ __launch_bounds__(256, 4) void attn_k(const u16* __restrict__ Qb,
                                                 const u16* __restrict__ Kb,
                                                 const u16* __restrict__ Vb,
                                                 const int* __restrict__ mask,
                                                 u16* __restrict__ Opart,
                                                 float* __restrict__ Lpart) {
  __shared__ __align__(16) u16 Ks[64 * 64];   // swizzled 16B chunks
  __shared__ __align__(16) u32 VsD[64 * 36];  // V^T dword (d,pr) at d*36 + (pr^((d>>3)<<2))

  int t = threadIdx.x, lane = t & 63, w = t >> 6;
  int c32 = lane & 31, hf = lane >> 5;
  int qt = blockIdx.x, head = blockIdx.y;
  int b = blockIdx.z & 1, qtr = blockIdx.z >> 1;
  int kv0 = qtr * 512;
  int gid = (b * 16 + head) * 16 + qt;

  // Q fragments direct from global (one-time): B-layout col=qrow, k=hf*8+j
  const u16* Qg = Qb + ((size_t)(b * CT + qt * 128 + w * 32 + c32)) * CD + head * CDH;
  bf16x8 qbf[4];
  #pragma unroll
  for (int kc = 0; kc < 4; kc++)
    qbf[kc] = *(const bf16x8*)(Qg + kc * 16 + hf * 8);

  // mask scan over this quarter
  const int* mk = mask + b * CT + kv0;
  int localAny = 0;
  for (int i = t; i < 512; i += 256) localAny |= (mk[i] == 0);
  int anyM = __syncthreads_or(localAny);

  f32x16 oacc[2];
  #pragma unroll
  for (int dt = 0; dt < 2; dt++)
    #pragma unroll
    for (int r = 0; r < 16; r++) oacc[dt][r] = 0.f;
  float lpA = 0.f, lpB = 0.f;

  const u16* Kg0 = Kb + ((size_t)(b * CT + kv0)) * CD + head * CDH;
  const u16* Vg0 = Vb + ((size_t)(b * CT + kv0)) * CD + head * CDH;

  // V prefetch (iter 0)
  int vpr = t >> 3, vdg = t & 7;
  const u16* VgT = Vg0 + (size_t)(2 * vpr) * CD + vdg * 8;
  uint4 va = *(const uint4*)VgT;
  uint4 vb2 = *(const uint4*)(VgT + CD);

  for (int kv = 0; kv < 512; kv += 64) {
    __syncthreads();
    // stage K (async DMA, swizzled)
    #pragma unroll
    for (int p = 0; p < 2; p++) {
      int idx = p * 256 + t;
      int row = idx >> 3, cc = (idx & 7) ^ (row & 7);
      gload_lds16(Kg0 + (size_t)(kv + row) * CD + cc * 8,
                  Ks + (size_t)(p * 256 + (t & 192)) * 8);
    }
    // stage V^T from prefetched regs (swizzled writes)
    {
      const u32* pa = (const u32*)&va;
      const u32* pb = (const u32*)&vb2;
      u32* dst = VsD + (size_t)vdg * 288 + (vpr ^ (vdg << 2));
      #pragma unroll
      for (int j = 0; j < 8; j++) {
        u32 lo_dw = pa[j >> 1], hi_dw = pb[j >> 1];
        u32 pkv = (j & 1) ? __builtin_amdgcn_perm(hi_dw, lo_dw, 0x07060302u)
                          : __builtin_amdgcn_perm(hi_dw, lo_dw, 0x05040100u);
        dst[j * 36] = pkv;
      }
    }
    __syncthreads();
    // prefetch next V tile
    if (kv + 64 < 512) {
      VgT = Vg0 + (size_t)(kv + 64 + 2 * vpr) * CD + vdg * 8;
      va = *(const uint4*)VgT;
      vb2 = *(const uint4*)(VgT + CD);
    }

    #pragma unroll
    for (int kt = 0; kt < 2; kt++) {
      // S^T tile: 32 keys x 32 qrows, K-dim 64 (already in exp2 domain)
      f32x16 sv;
      #pragma unroll
      for (int r = 0; r < 16; r++) sv[r] = 0.f;
      int key = kt * 32 + c32;
      #pragma unroll
      for (int kc = 0; kc < 4; kc++) {
        int ch = kc * 2 + hf;
        bf16x8 af = *(const bf16x8*)&Ks[key * 64 + ((ch ^ (key & 7)) * 8)];
        sv = __builtin_amdgcn_mfma_f32_32x32x16_bf16(af, qbf[kc], sv, 0, 0, 0);
      }
      // softmax in exp2 domain (no max-shift; scores bounded) + pack
      u32 pk[8];
      #pragma unroll
      for (int i = 0; i < 8; i++) {
        float x0 = sv[2 * i], x1 = sv[2 * i + 1];
        if (anyM) {
          int r0 = 2 * i, r1 = 2 * i + 1;
          int mi0 = kv + kt * 32 + (r0 & 3) + 8 * (r0 >> 2) + 4 * hf;
          int mi1 = kv + kt * 32 + (r1 & 3) + 8 * (r1 >> 2) + 4 * hf;
          x0 += mk[mi0] ? 0.f : -1.0e9f;
          x1 += mk[mi1] ? 0.f : -1.0e9f;
        }
        float p0 = fexp2(x0);
        float p1 = fexp2(x1);
        lpA += p0;
        lpB += p1;
        pk[i] = pk2(p0, p1);
      }
      // per 16-key chunk: build P B-frag via half-swaps, then PV MFMAs
      #pragma unroll
      for (int c = 0; c < 2; c++) {
        u32 d0 = pk[4 * c + 0], d2 = pk[4 * c + 2];
        u32 d1 = pk[4 * c + 1], d3 = pk[4 * c + 3];
        plswap(d0, d2, hf);
        plswap(d1, d3, hf);
        union { u32 u[4]; bf16x8 v; } pf;
        pf.u[0] = d0; pf.u[1] = d1; pf.u[2] = d2; pf.u[3] = d3;
        int prb = kt * 16 + c * 8 + hf * 4;
        #pragma unroll
        for (int dt = 0; dt < 2; dt++) {
          int d = dt * 32 + c32;
          const u32* vp = VsD + d * 36 + (prb ^ ((d >> 3) << 2));
          bf16x8 vf = *(const bf16x8*)vp;
          oacc[dt] = __builtin_amdgcn_mfma_f32_32x32x16_bf16(vf, pf.v, oacc[dt], 0, 0, 0);
        }
      }
    }
  }

  // epilogue: reduce l across halves (in-lane rows), normalize, store partial
  float lp = lpA + lpB;
  float lT = lp + __shfl_xor(lp, 32, 64);
  float linv = 1.f / lT;
  u16* Op = Opart + ((size_t)(qtr * 512 + gid) * 128 + w * 32 + c32) * 64;
  #pragma unroll
  for (int dt = 0; dt < 2; dt++) {
    #pragma unroll
    for (int g = 0; g < 4; g++) {
      float o0 = oacc[dt][4 * g + 0] * linv, o1 = oacc[dt][4 * g + 1] * linv;
      float o2 = oacc[dt][4 * g + 2] * linv, o3 = oacc[dt][4 * g + 3] * linv;
      uint2 pw;
      pw.x = pk2(o0, o1);
      pw.y = pk2(o2, o3);
      *(uint2*)(Op + dt * 32 + 8 * g + 4 * hf) = pw;
    }
  }
  if (lane < 32) Lpart[(size_t)(qtr * 512 + gid) * 128 + w * 32 + lane] = lT;
}

// ---------------- combine kv-split partials (4-way) ----------------
__global__ __launch_bounds__(256) void combine_k(const u16* __restrict__ Opart,
                                                 const float* __restrict__ Lpart,
                                                 u16* __restrict__ Ob) {
  int fid = blockIdx.x * 256 + threadIdx.x;  // 1M threads, 4 elems each
  int gid = fid >> 11;
  int rem = fid & 2047;
  int r = rem >> 4, d = (rem & 15) * 4;
  int b = gid >> 8, head = (gid >> 4) & 15, qt = gid & 15;
  float l[4], lsum = 0.f;
  uint2 A[4];
  #pragma unroll
  for (int q = 0; q < 4; q++) {
    size_t idx = (size_t)(q * 512 + gid) * 128 + r;
    l[q] = Lpart[idx];
    A[q] = *(const uint2*)(Opart + idx * 64 + d);
    lsum += l[q];
  }
  float inv = 1.f / lsum;
  float o0 = 0.f, o1 = 0.f, o2 = 0.f, o3 = 0.f;
  #pragma unroll
  for (int q = 0; q < 4; q++) {
    float wq = l[q] * inv;
    o0 += wq * b2f(A[q].x & 0xffffu);
    o1 += wq * b2f(A[q].x >> 16);
    o2 += wq * b2f(A[q].y & 0xffffu);
    o3 += wq * b2f(A[q].y >> 16);
  }
  uint2 pw;
  pw.x = pk2(o0, o1);
  pw.y = pk2(o2, o3);
  size_t trow = (size_t)b * CT + qt * 128 + r;
  *(uint2*)(Ob + trow * CD + head * CDH + d) = pw;
}

extern "C" void kernel_launch(void* const* d_in, const int* in_sizes, int n_in,
                              void* d_out, int out_size, void* d_ws, size_t ws_size,
                              hipStream_t stream) {
  const float* x  = (const float*)d_in[0];
  const int* mask = (const int*)d_in[1];
  const float* Wq = (const float*)d_in[2];
  const float* Wk = (const float*)d_in[3];
  const float* Wv = (const float*)d_in[4];
  const float* Wo = (const float*)d_in[5];
  float* out = (float*)d_out;

  u16* Xb    = (u16*)d_ws;                         // [4096][1024]
  u16* Wqkv  = Xb + (size_t)4096 * 1024;           // Wq^T|Wk^T|Wv^T|Wo^T [4096][1024]
  u16* WoT   = Wqkv + (size_t)3072 * 1024;
  u16* Qb    = Wqkv + (size_t)4096 * 1024;         // Q,K,V each [4096][1024]
  u16* Ob    = Qb + (size_t)3 * 4096 * 1024;       // attn out [4096][1024]
  u16* Opart = Ob + (size_t)4096 * 1024;           // [4*512][128][64] bf16
  float* Lpart = (float*)(Opart + (size_t)4 * 512 * 128 * 64);  // [4*512][128]

  const float EC = 0.18033688f;  // 0.125 * log2(e), folded into Q

  prep_k<<<8192, 256, 0, stream>>>(x, Wq, Wk, Wv, Wo, Xb, Wqkv);
  gemm_bt_k<u16><<<dim3(24, 32), 256, 0, stream>>>(Xb, Wqkv, Qb, 1024,
                                                   (size_t)4096 * 1024, EC);
  attn_k<<<dim3(16, 16, 8), 256, 0, stream>>>(Qb, Qb + (size_t)4096 * 1024,
                                              Qb + (size_t)2 * 4096 * 1024, mask,
                                              Opart, Lpart);
  combine_k<<<4096, 256, 0, stream>>>(Opart, Lpart, Ob);
  gemm_bt64_k<<<dim3(16, 32), 256, 0, stream>>>(Ob, WoT, out, 1024);
}

// Round 8
// 203.429 us; speedup vs baseline: 2.2735x; 1.0108x over previous
//
#include <hip/hip_runtime.h>
#include <stdint.h>

typedef unsigned short u16;
typedef unsigned int u32;

constexpr int CB = 2, CT = 2048, CH = 16, CDH = 64, CD = 1024;

typedef __attribute__((ext_vector_type(8))) short bf16x8;
typedef __attribute__((ext_vector_type(4))) float f32x4;
typedef __attribute__((ext_vector_type(16))) float f32x16;

typedef __attribute__((address_space(1))) const u32 as1_cu32;
typedef __attribute__((address_space(3))) u32 as3_u32;

__device__ __forceinline__ void gload_lds16(const void* g, void* l) {
  __builtin_amdgcn_global_load_lds((as1_cu32*)g, (as3_u32*)l, 16, 0, 0);
}

// fp32 -> bf16 round-to-nearest-even (finite inputs only)
__device__ __forceinline__ u16 f2b(float f) {
  u32 x = __float_as_uint(f);
  u32 r = (x + 0x7fffu + ((x >> 16) & 1u)) >> 16;
  return (u16)r;
}

#if __has_builtin(__builtin_amdgcn_cvt_pk_bf16_f32)
typedef __attribute__((ext_vector_type(2))) __bf16 v2bf;
__device__ __forceinline__ u32 pk2(float a, float b) {
  v2bf r = __builtin_amdgcn_cvt_pk_bf16_f32(a, b);
  union { v2bf v; u32 u; } cv; cv.v = r; return cv.u;
}
#else
__device__ __forceinline__ u32 pk2(float a, float b) {
  return (u32)f2b(a) | ((u32)f2b(b) << 16);
}
#endif

__device__ __forceinline__ float b2f(u32 lo16) { return __uint_as_float(lo16 << 16); }

// exp2 (v_exp_f32 is natively base-2)
__device__ __forceinline__ float fexp2(float x) {
#if __has_builtin(__builtin_amdgcn_exp2f)
  return __builtin_amdgcn_exp2f(x);
#else
  return __expf(x * 0.69314718056f);
#endif
}

// half-swap: a' = {a.lo32lanes, b.lo32lanes}, b' = {a.hi, b.hi}
#if __has_builtin(__builtin_amdgcn_permlane32_swap)
__device__ __forceinline__ void plswap(u32& a, u32& b, int) {
  auto r = __builtin_amdgcn_permlane32_swap(a, b, false, false);
  a = (u32)r[0]; b = (u32)r[1];
}
#else
__device__ __forceinline__ void plswap(u32& a, u32& b, int hf) {
  u32 ta = (u32)__shfl_xor((int)a, 32, 64);
  u32 tb = (u32)__shfl_xor((int)b, 32, 64);
  u32 na = hf ? tb : a;
  u32 nb = hf ? b : ta;
  a = na; b = nb;
}
#endif

// ---------------- fused prep: cast x + transpose/cast 4 weight mats ----------------
__global__ __launch_bounds__(256) void prep_k(const float* __restrict__ x,
                                              const float* __restrict__ Wq,
                                              const float* __restrict__ Wk,
                                              const float* __restrict__ Wv,
                                              const float* __restrict__ Wo,
                                              u16* __restrict__ Xb,
                                              u16* __restrict__ Wt) {
  __shared__ float tile[32][33];
  int bid = blockIdx.x, t = threadIdx.x;
  if (bid < 4096) {
    int i = bid * 256 + t;
    float4 v = ((const float4*)x)[i];
    ushort4 r;
    r.x = f2b(v.x); r.y = f2b(v.y); r.z = f2b(v.z); r.w = f2b(v.w);
    ((ushort4*)Xb)[i] = r;
  } else {
    int tid2 = bid - 4096;
    int mat = tid2 >> 10, b2 = tid2 & 1023;
    const float* W = (mat == 0) ? Wq : (mat == 1) ? Wk : (mat == 2) ? Wv : Wo;
    u16* dst = Wt + (size_t)mat * 1048576;
    int bx = (b2 & 31) * 32, by = (b2 >> 5) * 32;
    int tx = t & 31, ty = t >> 5;
    #pragma unroll
    for (int i = ty; i < 32; i += 8) tile[i][tx] = W[(size_t)(by + i) * CD + bx + tx];
    __syncthreads();
    #pragma unroll
    for (int i = ty; i < 32; i += 8)
      dst[(size_t)(bx + i) * CD + by + tx] = f2b(tile[tx][i]);
  }
}

// ---------------- QKV GEMM 128x128, BK=64, coalesced LDS epilogue ----------------
// MFMA operands swapped (D = Bt_frag * A_frag): lane holds token=col(m), 4
// consecutive outcols per acc reg -> packed b64 LDS writes, b128 read-back,
// global_store_dwordx4 (r7's scalar-store epilogue was ~100us of VMEM issue).
__global__ __launch_bounds__(256) void gemm_qkv_k(const u16* __restrict__ A,
                                                  const u16* __restrict__ Bt,
                                                  u16* __restrict__ Cout,
                                                  int K, size_t subStride,
                                                  float scaleQ) {
  __shared__ __align__(16) u16 smem[16384];  // As 16KB | Bs 16KB; epilogue 32KB
  u16* As = smem;
  u16* Bs = smem + 8192;
  int t = threadIdx.x;
  int lane = t & 63, w = t >> 6;
  int m = lane & 15, quad = lane >> 4;
  int wrow = w >> 1, wcol = w & 1;
  int m0 = blockIdx.y * 128, n0 = blockIdx.x * 128;

  f32x4 acc[4][4];
  #pragma unroll
  for (int i = 0; i < 4; i++)
    #pragma unroll
    for (int j = 0; j < 4; j++) acc[i][j] = (f32x4){0.f, 0.f, 0.f, 0.f};

  for (int k0 = 0; k0 < K; k0 += 64) {
    __syncthreads();
    #pragma unroll
    for (int p = 0; p < 4; p++) {
      int idx = p * 256 + t;
      int row = idx >> 3, cc = (idx & 7) ^ (row & 7);
      gload_lds16(A + (size_t)(m0 + row) * K + k0 + cc * 8,
                  As + (size_t)(p * 256 + (t & 192)) * 8);
      gload_lds16(Bt + (size_t)(n0 + row) * K + k0 + cc * 8,
                  Bs + (size_t)(p * 256 + (t & 192)) * 8);
    }
    __syncthreads();
    #pragma unroll
    for (int kk = 0; kk < 2; kk++) {
      bf16x8 af[4], bfr[4];
      #pragma unroll
      for (int mt = 0; mt < 4; mt++) {
        int r = wrow * 64 + mt * 16 + m;
        af[mt] = *(const bf16x8*)&As[r * 64 + (((kk * 4 + quad) ^ (r & 7)) * 8)];
      }
      #pragma unroll
      for (int nt = 0; nt < 4; nt++) {
        int r = wcol * 64 + nt * 16 + m;
        bfr[nt] = *(const bf16x8*)&Bs[r * 64 + (((kk * 4 + quad) ^ (r & 7)) * 8)];
      }
      #pragma unroll
      for (int mt = 0; mt < 4; mt++)
        #pragma unroll
        for (int nt = 0; nt < 4; nt++)
          acc[mt][nt] = __builtin_amdgcn_mfma_f32_16x16x32_bf16(bfr[nt], af[mt],
                                                                acc[mt][nt], 0, 0, 0);
    }
  }

  // epilogue: acc[mt][nt] holds token r=(m), outcols c..c+3 in regs
  float s = (n0 < 1024) ? scaleQ : 1.0f;
  __syncthreads();
  u32* Ls = (u32*)smem;  // [128 rows][64 dw], 16B-chunk XOR swizzle by row&15
  #pragma unroll
  for (int mt = 0; mt < 4; mt++) {
    int r = wrow * 64 + mt * 16 + m;
    #pragma unroll
    for (int nt = 0; nt < 4; nt++) {
      int c = wcol * 64 + nt * 16 + quad * 4;
      uint2 pw;
      pw.x = pk2(acc[mt][nt][0] * s, acc[mt][nt][1] * s);
      pw.y = pk2(acc[mt][nt][2] * s, acc[mt][nt][3] * s);
      int chunk = c >> 3, half = (c >> 2) & 1;
      *(uint2*)(Ls + r * 64 + (((chunk ^ (r & 15)) << 2) + (half << 1))) = pw;
    }
  }
  __syncthreads();
  #pragma unroll
  for (int i = 0; i < 8; i++) {
    int row = i * 16 + (t >> 4), chunk = t & 15;
    uint4 v = *(const uint4*)(Ls + row * 64 + ((chunk ^ (row & 15)) << 2));
    int cg = n0 + chunk * 8;
    u16* outp = Cout + (size_t)(cg >> 10) * subStride + (size_t)(m0 + row) * CD + (cg & 1023);
    *(uint4*)outp = v;
  }
}

// ---------------- out-proj GEMM 128x64, BK=64, coalesced fp32 epilogue ----------------
__global__ __launch_bounds__(256) void gemm_out_k(const u16* __restrict__ A,
                                                  const u16* __restrict__ Bt,
                                                  float* __restrict__ Cout, int K) {
  __shared__ __align__(16) u16 smem[16384];  // As 16KB | Bs 8KB; epilogue fp32 32KB
  u16* As = smem;
  u16* Bs = smem + 8192;
  int t = threadIdx.x;
  int lane = t & 63, w = t >> 6;
  int m = lane & 15, quad = lane >> 4;
  int wrow = w >> 1, wcol = w & 1;
  int m0 = blockIdx.y * 128, n0 = blockIdx.x * 64;

  f32x4 acc[4][2];
  #pragma unroll
  for (int i = 0; i < 4; i++)
    #pragma unroll
    for (int j = 0; j < 2; j++) acc[i][j] = (f32x4){0.f, 0.f, 0.f, 0.f};

  for (int k0 = 0; k0 < K; k0 += 64) {
    __syncthreads();
    #pragma unroll
    for (int p = 0; p < 4; p++) {
      int idx = p * 256 + t;
      int row = idx >> 3, cc = (idx & 7) ^ (row & 7);
      gload_lds16(A + (size_t)(m0 + row) * K + k0 + cc * 8,
                  As + (size_t)(p * 256 + (t & 192)) * 8);
    }
    #pragma unroll
    for (int p = 0; p < 2; p++) {
      int idx = p * 256 + t;
      int row = idx >> 3, cc = (idx & 7) ^ (row & 7);
      gload_lds16(Bt + (size_t)(n0 + row) * K + k0 + cc * 8,
                  Bs + (size_t)(p * 256 + (t & 192)) * 8);
    }
    __syncthreads();
    #pragma unroll
    for (int kk = 0; kk < 2; kk++) {
      bf16x8 af[4], bfr[2];
      #pragma unroll
      for (int mt = 0; mt < 4; mt++) {
        int r = wrow * 64 + mt * 16 + m;
        af[mt] = *(const bf16x8*)&As[r * 64 + (((kk * 4 + quad) ^ (r & 7)) * 8)];
      }
      #pragma unroll
      for (int nt = 0; nt < 2; nt++) {
        int r = wcol * 32 + nt * 16 + m;
        bfr[nt] = *(const bf16x8*)&Bs[r * 64 + (((kk * 4 + quad) ^ (r & 7)) * 8)];
      }
      #pragma unroll
      for (int mt = 0; mt < 4; mt++)
        #pragma unroll
        for (int nt = 0; nt < 2; nt++)
          acc[mt][nt] = __builtin_amdgcn_mfma_f32_16x16x32_bf16(bfr[nt], af[mt],
                                                                acc[mt][nt], 0, 0, 0);
    }
  }

  __syncthreads();
  float* Ls = (float*)smem;  // [128 rows][64 fp32], 16B-chunk XOR swizzle
  #pragma unroll
  for (int mt = 0; mt < 4; mt++) {
    int r = wrow * 64 + mt * 16 + m;
    #pragma unroll
    for (int nt = 0; nt < 2; nt++) {
      int c = wcol * 32 + nt * 16 + quad * 4;
      int chunk = c >> 2;
      *(f32x4*)(Ls + r * 64 + ((chunk ^ (r & 15)) << 2)) = acc[mt][nt];
    }
  }
  __syncthreads();
  #pragma unroll
  for (int i = 0; i < 8; i++) {
    int row = i * 16 + (t >> 4), chunk = t & 15;
    f32x4 v = *(const f32x4*)(Ls + row * 64 + ((chunk ^ (row & 15)) << 2));
    *(f32x4*)(Cout + (size_t)(m0 + row) * CD + n0 + chunk * 4) = v;
  }
}

// ---------------- flash attention, 32x32 MFMA, kv-split x4, no P-LDS ----------------
// Q pre-scaled by 0.125*log2(e) in QKV epilogue -> S accumulates in exp2 domain.
// (256,4): (256,8) forced VGPR=32 -> spill storm (r5).
__global__ __launch_bounds__(256, 4) void attn_k(const u16* __restrict__ Qb,
                                                 const u16* __restrict__ Kb,
                                                 const u16* __restrict__ Vb,
                                                 const int* __restrict__ mask,
                                                 u16* __restrict__ Opart,
                                                 float* __restrict__ Lpart) {
  __shared__ __align__(16) u16 Ks[64 * 64];   // swizzled 16B chunks
  __shared__ __align__(16) u32 VsD[64 * 36];  // V^T dword (d,pr) at d*36 + (pr^((d>>3)<<2))

  int t = threadIdx.x, lane = t & 63, w = t >> 6;
  int c32 = lane & 31, hf = lane >> 5;
  int qt = blockIdx.x, head = blockIdx.y;
  int b = blockIdx.z & 1, qtr = blockIdx.z >> 1;
  int kv0 = qtr * 512;
  int gid = (b * 16 + head) * 16 + qt;

  // Q fragments direct from global (one-time): B-layout col=qrow, k=hf*8+j
  const u16* Qg = Qb + ((size_t)(b * CT + qt * 128 + w * 32 + c32)) * CD + head * CDH;
  bf16x8 qbf[4];
  #pragma unroll
  for (int kc = 0; kc < 4; kc++)
    qbf[kc] = *(const bf16x8*)(Qg + kc * 16 + hf * 8);

  // mask scan over this quarter
  const int* mk = mask + b * CT + kv0;
  int localAny = 0;
  for (int i = t; i < 512; i += 256) localAny |= (mk[i] == 0);
  int anyM = __syncthreads_or(localAny);

  f32x16 oacc[2];
  #pragma unroll
  for (int dt = 0; dt < 2; dt++)
    #pragma unroll
    for (int r = 0; r < 16; r++) oacc[dt][r] = 0.f;
  float lpA = 0.f, lpB = 0.f;

  const u16* Kg0 = Kb + ((size_t)(b * CT + kv0)) * CD + head * CDH;
  const u16* Vg0 = Vb + ((size_t)(b * CT + kv0)) * CD + head * CDH;

  // V prefetch (iter 0)
  int vpr = t >> 3, vdg = t & 7;
  const u16* VgT = Vg0 + (size_t)(2 * vpr) * CD + vdg * 8;
  uint4 va = *(const uint4*)VgT;
  uint4 vb2 = *(const uint4*)(VgT + CD);

  for (int kv = 0; kv < 512; kv += 64) {
    __syncthreads();
    // stage K (async DMA, swizzled)
    #pragma unroll
    for (int p = 0; p < 2; p++) {
      int idx = p * 256 + t;
      int row = idx >> 3, cc = (idx & 7) ^ (row & 7);
      gload_lds16(Kg0 + (size_t)(kv + row) * CD + cc * 8,
                  Ks + (size_t)(p * 256 + (t & 192)) * 8);
    }
    // stage V^T from prefetched regs (swizzled writes)
    {
      const u32* pa = (const u32*)&va;
      const u32* pb = (const u32*)&vb2;
      u32* dst = VsD + (size_t)vdg * 288 + (vpr ^ (vdg << 2));
      #pragma unroll
      for (int j = 0; j < 8; j++) {
        u32 lo_dw = pa[j >> 1], hi_dw = pb[j >> 1];
        u32 pkv = (j & 1) ? __builtin_amdgcn_perm(hi_dw, lo_dw, 0x07060302u)
                          : __builtin_amdgcn_perm(hi_dw, lo_dw, 0x05040100u);
        dst[j * 36] = pkv;
      }
    }
    __syncthreads();
    // prefetch next V tile
    if (kv + 64 < 512) {
      VgT = Vg0 + (size_t)(kv + 64 + 2 * vpr) * CD + vdg * 8;
      va = *(const uint4*)VgT;
      vb2 = *(const uint4*)(VgT + CD);
    }

    #pragma unroll
    for (int kt = 0; kt < 2; kt++) {
      // S^T tile: 32 keys x 32 qrows, K-dim 64 (already in exp2 domain)
      f32x16 sv;
      #pragma unroll
      for (int r = 0; r < 16; r++) sv[r] = 0.f;
      int key = kt * 32 + c32;
      #pragma unroll
      for (int kc = 0; kc < 4; kc++) {
        int ch = kc * 2 + hf;
        bf16x8 af = *(const bf16x8*)&Ks[key * 64 + ((ch ^ (key & 7)) * 8)];
        sv = __builtin_amdgcn_mfma_f32_32x32x16_bf16(af, qbf[kc], sv, 0, 0, 0);
      }
      // softmax in exp2 domain (no max-shift; scores bounded) + pack
      u32 pk[8];
      #pragma unroll
      for (int i = 0; i < 8; i++) {
        float x0 = sv[2 * i], x1 = sv[2 * i + 1];
        if (anyM) {
          int r0 = 2 * i, r1 = 2 * i + 1;
          int mi0 = kv + kt * 32 + (r0 & 3) + 8 * (r0 >> 2) + 4 * hf;
          int mi1 = kv + kt * 32 + (r1 & 3) + 8 * (r1 >> 2) + 4 * hf;
          x0 += mk[mi0] ? 0.f : -1.0e9f;
          x1 += mk[mi1] ? 0.f : -1.0e9f;
        }
        float p0 = fexp2(x0);
        float p1 = fexp2(x1);
        lpA += p0;
        lpB += p1;
        pk[i] = pk2(p0, p1);
      }
      // per 16-key chunk: build P B-frag via half-swaps, then PV MFMAs
      #pragma unroll
      for (int c = 0; c < 2; c++) {
        u32 d0 = pk[4 * c + 0], d2 = pk[4 * c + 2];
        u32 d1 = pk[4 * c + 1], d3 = pk[4 * c + 3];
        plswap(d0, d2, hf);
        plswap(d1, d3, hf);
        union { u32 u[4]; bf16x8 v; } pf;
        pf.u[0] = d0; pf.u[1] = d1; pf.u[2] = d2; pf.u[3] = d3;
        int prb = kt * 16 + c * 8 + hf * 4;
        #pragma unroll
        for (int dt = 0; dt < 2; dt++) {
          int d = dt * 32 + c32;
          const u32* vp = VsD + d * 36 + (prb ^ ((d >> 3) << 2));
          bf16x8 vf = *(const bf16x8*)vp;
          oacc[dt] = __builtin_amdgcn_mfma_f32_32x32x16_bf16(vf, pf.v, oacc[dt], 0, 0, 0);
        }
      }
    }
  }

  // epilogue: reduce l across halves (in-lane rows), normalize, store partial
  float lp = lpA + lpB;
  float lT = lp + __shfl_xor(lp, 32, 64);
  float linv = 1.f / lT;
  u16* Op = Opart + ((size_t)(qtr * 512 + gid) * 128 + w * 32 + c32) * 64;
  #pragma unroll
  for (int dt = 0; dt < 2; dt++) {
    #pragma unroll
    for (int g = 0; g < 4; g++) {
      float o0 = oacc[dt][4 * g + 0] * linv, o1 = oacc[dt][4 * g + 1] * linv;
      float o2 = oacc[dt][4 * g + 2] * linv, o3 = oacc[dt][4 * g + 3] * linv;
      uint2 pw;
      pw.x = pk2(o0, o1);
      pw.y = pk2(o2, o3);
      *(uint2*)(Op + dt * 32 + 8 * g + 4 * hf) = pw;
    }
  }
  if (lane < 32) Lpart[(size_t)(qtr * 512 + gid) * 128 + w * 32 + lane] = lT;
}

// ---------------- combine kv-split partials (4-way) ----------------
__global__ __launch_bounds__(256) void combine_k(const u16* __restrict__ Opart,
                                                 const float* __restrict__ Lpart,
                                                 u16* __restrict__ Ob) {
  int fid = blockIdx.x * 256 + threadIdx.x;  // 1M threads, 4 elems each
  int gid = fid >> 11;
  int rem = fid & 2047;
  int r = rem >> 4, d = (rem & 15) * 4;
  int b = gid >> 8, head = (gid >> 4) & 15, qt = gid & 15;
  float l[4], lsum = 0.f;
  uint2 A[4];
  #pragma unroll
  for (int q = 0; q < 4; q++) {
    size_t idx = (size_t)(q * 512 + gid) * 128 + r;
    l[q] = Lpart[idx];
    A[q] = *(const uint2*)(Opart + idx * 64 + d);
    lsum += l[q];
  }
  float inv = 1.f / lsum;
  float o0 = 0.f, o1 = 0.f, o2 = 0.f, o3 = 0.f;
  #pragma unroll
  for (int q = 0; q < 4; q++) {
    float wq = l[q] * inv;
    o0 += wq * b2f(A[q].x & 0xffffu);
    o1 += wq * b2f(A[q].x >> 16);
    o2 += wq * b2f(A[q].y & 0xffffu);
    o3 += wq * b2f(A[q].y >> 16);
  }
  uint2 pw;
  pw.x = pk2(o0, o1);
  pw.y = pk2(o2, o3);
  size_t trow = (size_t)b * CT + qt * 128 + r;
  *(uint2*)(Ob + trow * CD + head * CDH + d) = pw;
}

extern "C" void kernel_launch(void* const* d_in, const int* in_sizes, int n_in,
                              void* d_out, int out_size, void* d_ws, size_t ws_size,
                              hipStream_t stream) {
  const float* x  = (const float*)d_in[0];
  const int* mask = (const int*)d_in[1];
  const float* Wq = (const float*)d_in[2];
  const float* Wk = (const float*)d_in[3];
  const float* Wv = (const float*)d_in[4];
  const float* Wo = (const float*)d_in[5];
  float* out = (float*)d_out;

  u16* Xb    = (u16*)d_ws;                         // [4096][1024]
  u16* Wqkv  = Xb + (size_t)4096 * 1024;           // Wq^T|Wk^T|Wv^T|Wo^T [4096][1024]
  u16* WoT   = Wqkv + (size_t)3072 * 1024;
  u16* Qb    = Wqkv + (size_t)4096 * 1024;         // Q,K,V each [4096][1024]
  u16* Ob    = Qb + (size_t)3 * 4096 * 1024;       // attn out [4096][1024]
  u16* Opart = Ob + (size_t)4096 * 1024;           // [4*512][128][64] bf16
  float* Lpart = (float*)(Opart + (size_t)4 * 512 * 128 * 64);  // [4*512][128]

  const float EC = 0.18033688f;  // 0.125 * log2(e), folded into Q

  prep_k<<<8192, 256, 0, stream>>>(x, Wq, Wk, Wv, Wo, Xb, Wqkv);
  gemm_qkv_k<<<dim3(24, 32), 256, 0, stream>>>(Xb, Wqkv, Qb, 1024,
                                               (size_t)4096 * 1024, EC);
  attn_k<<<dim3(16, 16, 8), 256, 0, stream>>>(Qb, Qb + (size_t)4096 * 1024,
                                              Qb + (size_t)2 * 4096 * 1024, mask,
                                              Opart, Lpart);
  combine_k<<<4096, 256, 0, stream>>>(Opart, Lpart, Ob);
  gemm_out_k<<<dim3(16, 32), 256, 0, stream>>>(Ob, WoT, out, 1024);
}